// Round 5
// baseline (4571.398 us; speedup 1.0000x reference)
//
#include <hip/hip_runtime.h>
#include <stdint.h>

#define HID 512
#define IND 256
#define OUTD 256
#define BROWS 64

typedef __attribute__((ext_vector_type(8))) short short8;   // 8 bf16
typedef __attribute__((ext_vector_type(4))) short short4v;  // 4 bf16
typedef __attribute__((ext_vector_type(4))) float f32x4;

#define MFMA16(a,b,c) __builtin_amdgcn_mfma_f32_16x16x32_bf16(a,b,c,0,0,0)

__device__ __forceinline__ short f2bf(float f){
  uint32_t u = __builtin_bit_cast(uint32_t, f);
  u += 0x7FFFu + ((u>>16)&1u);
  return (short)(u>>16);
}
__device__ __forceinline__ float bf2f(short s){
  uint32_t u = ((uint32_t)(uint16_t)s) << 16;
  return __builtin_bit_cast(float, u);
}
__device__ __forceinline__ float tanh_fast(float x){
  float e = __builtin_amdgcn_exp2f(x * 2.88539008177792681472f);
  return __builtin_fmaf(-2.0f, __builtin_amdgcn_rcpf(e + 1.0f), 1.0f);
}
__device__ __forceinline__ float neigh(float v){
  // lane^1 exchange via DPP quad_perm [1,0,3,2]
  return __builtin_bit_cast(float,
      __builtin_amdgcn_mov_dpp(__builtin_bit_cast(int, v), 0xB1, 0xF, 0xF, true));
}
__device__ __forceinline__ uint32_t axor(uint32_t b){ return b ^ (((b>>7)&7u)<<4); }

// ---------------- sigma: one power-iteration step, one block per matrix ----------------
__global__ void sigma_kernel(const float* __restrict__ lw, const float* __restrict__ lu,
                             const float* __restrict__ ow, const float* __restrict__ ou,
                             float* __restrict__ invs)
{
  __shared__ float sv[HID];
  __shared__ float red[8];
  const int g = threadIdx.x;  // 512 threads
  const int m = blockIdx.x;   // 0..3
  const float* W = (m < 3) ? (lw + (size_t)m*HID*HID) : ow;
  const float* u = (m < 3) ? (lu + m*HID) : ou;
  float t1 = 0.f;
  for (int k = 0; k < HID; ++k) t1 += W[(size_t)k*HID + g] * u[k];
  float ss = t1*t1;
  #pragma unroll
  for (int d = 32; d; d >>= 1) ss += __shfl_xor(ss, d);
  if ((g & 63) == 0) red[g >> 6] = ss;
  __syncthreads();
  float tot = 0.f;
  #pragma unroll
  for (int i = 0; i < 8; ++i) tot += red[i];
  float nrm = sqrtf(tot);
  sv[g] = t1 / (nrm + 1e-12f);
  __syncthreads();
  float n = 0.f;
  const float* Wr = W + (size_t)g*HID;
  for (int k = 0; k < HID; ++k) n += Wr[k] * sv[k];
  float ss2 = n*n;
  #pragma unroll
  for (int d = 32; d; d >>= 1) ss2 += __shfl_xor(ss2, d);
  if ((g & 63) == 0) red[g >> 6] = ss2;
  __syncthreads();
  float tot2 = 0.f;
  #pragma unroll
  for (int i = 0; i < 8; ++i) tot2 += red[i];
  float nn = sqrtf(tot2);
  float sigma = tot2 / (nn + 1e-12f);   // dot(u2, Wv)
  if (g == 0) invs[m] = 1.0f / sigma;
}

// ---------------- weight packing (hi + lo bf16), MFMA-frag-sequential ----------------
// B-frag (16x16x32): lane l holds B[k = kt*32 + (l>>4)*8 + j][col = ctg*16 + (l&15)],
// element index ((kt*NCT+ctg)*64 + l)*8 + j.
__global__ void pack_wsum(const float* __restrict__ lw, const float* __restrict__ invs,
                          short* __restrict__ pwh, short* __restrict__ pwl)
{
  int i = blockIdx.x*blockDim.x + threadIdx.x;   // < 512*512
  int j = i & 7, lane = (i >> 3) & 63, f = i >> 9;
  int kt = f >> 5, ctg = f & 31;                 // NCT = 32
  int k = kt*32 + (lane >> 4)*8 + j;
  int g = ctg*16 + (lane & 15);
  size_t idx = (size_t)g*HID + k;
  float v = lw[idx]*invs[0] + lw[262144 + idx]*invs[1] + lw[524288 + idx]*invs[2];
  short hi = f2bf(v);
  pwh[i] = hi;
  pwl[i] = f2bf(v - bf2f(hi));
}

template<int K, int N, bool WLO>
__global__ void pack_b(const float* __restrict__ W, short* __restrict__ pbh,
                       short* __restrict__ pbl)
{
  int i = blockIdx.x*blockDim.x + threadIdx.x;   // < K*N
  int j = i & 7, lane = (i >> 3) & 63, f = i >> 9;
  constexpr int NCT = N/16;
  int kt = f / NCT, ctg = f % NCT;
  int k = kt*32 + (lane >> 4)*8 + j;
  int c = ctg*16 + (lane & 15);
  float v = W[(size_t)c*K + k];
  short hi = f2bf(v);
  pbh[i] = hi;
  if (WLO) pbl[i] = f2bf(v - bf2f(hi));
}

__global__ void pack_small(const float* __restrict__ lb, const float* __restrict__ ow,
                           const float* __restrict__ invs,
                           float* __restrict__ bsum, float* __restrict__ cs, float* __restrict__ cn)
{
  int g = blockIdx.x*blockDim.x + threadIdx.x;
  if (g >= HID) return;
  bsum[g] = lb[g] + lb[HID + g] + lb[2*HID + g];
  float is = invs[3];
  cs[g] = ow[(size_t)g*HID + g] * is;        // osc_sn[g][g]
  cn[g] = ow[(size_t)g*HID + (g^1)] * is;    // osc_sn[g][g^1]
}

// ---------------- fused main: 64-row block, 512 threads, split-precision matmuls ----------------
// __launch_bounds__(512) ONLY (no 2nd arg, no extra attrs): HIP maps it to
// amdgpu-flat-work-group-size(1,512), replacing hipcc's default (1,1024).
// A 512-thread WG needs just 2 waves/SIMD co-resident -> 256-VGPR budget, so
// the ~230-reg live state (h64+xe64+acc32+frags) fits with ZERO spills.
// (launch_bounds(512,2) and amdgpu_waves_per_eu both ended at a 128 cap.)
__global__ void __launch_bounds__(512) fused_main(
    const float* __restrict__ x,
    const float* __restrict__ winb,
    const float* __restrict__ headb,
    const int*  __restrict__ stepsp,
    const short* __restrict__ packWh,
    const short* __restrict__ packWl,
    const short* __restrict__ packIh,
    const short* __restrict__ packIl,
    const short* __restrict__ packHd,
    const float* __restrict__ bsumA,
    const float* __restrict__ csA,
    const float* __restrict__ cnA,
    float* __restrict__ out)
{
  extern __shared__ char lds[];     // 128 KiB: [A_hi 64K][A_lo 64K], frag-major
  char* ldsHi = lds;
  char* ldsLo = lds + 65536;
  const int tid  = threadIdx.x;
  const int lane = tid & 63;
  const int l15  = lane & 15;
  const int ql   = lane >> 4;       // 0..3
  const int wc   = tid >> 6;        // 0..7 (col group: 64 cols), all waves cover rows 0..63
  const int rb   = blockIdx.x;

  // ---- stage x tile -> LDS bf16 hi/lo, frag-major [rtg 0..3][kt 0..7] (32 KiB each) ----
  {
    const float* xb = x + (size_t)rb*BROWS*IND;
    #pragma unroll
    for (int i = 0; i < 8; ++i) {
      int fi  = i*512 + tid;        // 4096 float4s
      int row = fi >> 6;            // 0..63
      int c   = (fi & 63)*4;        // 0..252
      f32x4 v = *(const f32x4*)(xb + (size_t)row*IND + c);
      short4v hi4, lo4;
      #pragma unroll
      for (int j = 0; j < 4; ++j) {
        short h16 = f2bf(v[j]);
        hi4[j] = h16;
        lo4[j] = f2bf(v[j] - bf2f(h16));
      }
      int rtg = row >> 4, kt = c >> 5, qd = (c >> 3) & 3;
      uint32_t byte = (uint32_t)(((rtg*8 + kt)*1024) + (qd*16 + (row & 15))*16 + (c & 7)*2);
      *(short4v*)(ldsHi + axor(byte)) = hi4;
      *(short4v*)(ldsLo + axor(byte)) = lo4;
    }
  }
  __syncthreads();

  const int nsteps = stepsp[0];

  // per-lane column constants (4 col tiles of 16)
  int colc[4]; float bs[4], cs_[4], cn_[4], wb[4];
  #pragma unroll
  for (int ct = 0; ct < 4; ++ct) {
    int c = wc*64 + ct*16 + l15;
    colc[ct] = c; bs[ct] = bsumA[c]; cs_[ct] = csA[c]; cn_[ct] = cnA[c]; wb[ct] = winb[c];
  }

  // byte-base pointers for frag-sequential weight streams (per-lane)
  const char* baseWh = (const char*)packWh + (size_t)wc*4096 + (size_t)lane*16;
  const char* baseWl = (const char*)packWl + (size_t)wc*4096 + (size_t)lane*16;

  // ---- x_emb = x @ W_in^T + W_in_b + b_sum  (3-pass split precision) ----
  f32x4 xe[4][4];
  #pragma unroll
  for (int rt = 0; rt < 4; ++rt)
    #pragma unroll
    for (int ct = 0; ct < 4; ++ct) {
      float s = wb[ct] + bs[ct];
      f32x4 z; z[0]=s; z[1]=s; z[2]=s; z[3]=s;
      xe[rt][ct] = z;
    }
  {
    const char* pIh = (const char*)packIh + (size_t)wc*4096 + (size_t)lane*16;
    const char* pIl = (const char*)packIl + (size_t)wc*4096 + (size_t)lane*16;
    #pragma unroll 2
    for (int kt = 0; kt < 8; ++kt) {
      short8 ah[4], al[4];
      #pragma unroll
      for (int rt = 0; rt < 4; ++rt) {
        uint32_t byte = axor((uint32_t)((rt*8 + kt)*1024 + lane*16));
        ah[rt] = *(const short8*)(ldsHi + byte);
        al[rt] = *(const short8*)(ldsLo + byte);
      }
      #pragma unroll
      for (int ct = 0; ct < 4; ++ct) {
        short8 bh = *(const short8*)(pIh + ct*1024);
        short8 bl = *(const short8*)(pIl + ct*1024);
        #pragma unroll
        for (int rt = 0; rt < 4; ++rt) {
          xe[rt][ct] = MFMA16(ah[rt], bh, xe[rt][ct]);
          xe[rt][ct] = MFMA16(al[rt], bh, xe[rt][ct]);
          xe[rt][ct] = MFMA16(ah[rt], bl, xe[rt][ct]);
        }
      }
      pIh += 32768; pIl += 32768;
    }
  }
  __syncthreads();

  // ---- h init: h1 = 0.5*tanh(xe) ----
  f32x4 h[4][4];
  #pragma unroll
  for (int rt = 0; rt < 4; ++rt)
    #pragma unroll
    for (int ct = 0; ct < 4; ++ct)
      #pragma unroll
      for (int r = 0; r < 4; ++r)
        h[rt][ct][r] = (nsteps >= 1) ? 0.5f * tanh_fast(xe[rt][ct][r]) : 0.f;

  // write-address components: col part + ql
  uint32_t wbase[4];
  #pragma unroll
  for (int ct = 0; ct < 4; ++ct) {
    int c = colc[ct];
    wbase[ct] = (uint32_t)(((c >> 5)*1024) + (((c >> 3) & 3)*256) + ((c & 7)*2) + ql*64);
  }

  // ---- recurrence steps 2..nsteps ----
  for (int s = 1; s < nsteps; ++s) {
    // t = tanh(h) -> LDS hi/lo A-tiles
    #pragma unroll
    for (int rt = 0; rt < 4; ++rt) {
      uint32_t rcomp = (uint32_t)(rt*16384);
      #pragma unroll
      for (int ct = 0; ct < 4; ++ct)
        #pragma unroll
        for (int r = 0; r < 4; ++r) {
          float t = tanh_fast(h[rt][ct][r]);
          short hi16 = f2bf(t);
          uint32_t byte = axor(rcomp + wbase[ct] + (uint32_t)(r*16));
          *(short*)(ldsHi + byte) = hi16;
          *(short*)(ldsLo + byte) = f2bf(t - bf2f(hi16));
        }
    }
    __syncthreads();

    #pragma unroll
    for (int ch = 0; ch < 2; ++ch) {      // ct-halves: acc only 32 regs live
      f32x4 acc[4][2];
      #pragma unroll
      for (int rt = 0; rt < 4; ++rt)
        #pragma unroll
        for (int c2 = 0; c2 < 2; ++c2) {
          int ct = ch*2 + c2;
          #pragma unroll
          for (int r = 0; r < 4; ++r) {
            float hv = h[rt][ct][r];
            acc[rt][c2][r] = __builtin_fmaf(cs_[ct], hv,
                               __builtin_fmaf(cn_[ct], neigh(hv), xe[rt][ct][r]));
          }
        }
      const char* pWh_ = baseWh + ch*2048;
      const char* pWl_ = baseWl + ch*2048;
      #pragma unroll 2
      for (int kt = 0; kt < 16; ++kt) {
        short8 ah[4], al[4];
        #pragma unroll
        for (int rt = 0; rt < 4; ++rt) {
          uint32_t byte = axor((uint32_t)((rt*16 + kt)*1024 + lane*16));
          ah[rt] = *(const short8*)(ldsHi + byte);
          al[rt] = *(const short8*)(ldsLo + byte);
        }
        #pragma unroll
        for (int c2 = 0; c2 < 2; ++c2) {
          short8 bh = *(const short8*)(pWh_ + c2*1024);
          short8 bl = *(const short8*)(pWl_ + c2*1024);
          #pragma unroll
          for (int rt = 0; rt < 4; ++rt) {
            acc[rt][c2] = MFMA16(ah[rt], bh, acc[rt][c2]);
            acc[rt][c2] = MFMA16(al[rt], bh, acc[rt][c2]);
            acc[rt][c2] = MFMA16(ah[rt], bl, acc[rt][c2]);
          }
        }
        pWh_ += 32768; pWl_ += 32768;
      }
      #pragma unroll
      for (int rt = 0; rt < 4; ++rt)
        #pragma unroll
        for (int c2 = 0; c2 < 2; ++c2) {
          int ct = ch*2 + c2;
          #pragma unroll
          for (int r = 0; r < 4; ++r)
            h[rt][ct][r] = __builtin_fmaf(0.5f, tanh_fast(acc[rt][c2][r]), 0.5f*h[rt][ct][r]);
        }
    }
    __syncthreads();
  }

  // ---- head: out = h @ head_w^T + head_b  (A split hi/lo, W single bf16) ----
  #pragma unroll
  for (int rt = 0; rt < 4; ++rt) {
    uint32_t rcomp = (uint32_t)(rt*16384);
    #pragma unroll
    for (int ct = 0; ct < 4; ++ct)
      #pragma unroll
      for (int r = 0; r < 4; ++r) {
        float hv = h[rt][ct][r];
        short hi16 = f2bf(hv);
        uint32_t byte = axor(rcomp + wbase[ct] + (uint32_t)(r*16));
        *(short*)(ldsHi + byte) = hi16;
        *(short*)(ldsLo + byte) = f2bf(hv - bf2f(hi16));
      }
  }
  __syncthreads();

  int oc[2]; float hbv[2];
  #pragma unroll
  for (int c2 = 0; c2 < 2; ++c2) { oc[c2] = wc*32 + c2*16 + l15; hbv[c2] = headb[oc[c2]]; }
  f32x4 o[4][2];
  #pragma unroll
  for (int rt = 0; rt < 4; ++rt)
    #pragma unroll
    for (int c2 = 0; c2 < 2; ++c2) {
      f32x4 z; z[0]=hbv[c2]; z[1]=hbv[c2]; z[2]=hbv[c2]; z[3]=hbv[c2];
      o[rt][c2] = z;
    }
  {
    const char* pHd = (const char*)packHd + (size_t)wc*2048 + (size_t)lane*16;
    #pragma unroll 2
    for (int kt = 0; kt < 16; ++kt) {
      short8 ah[4], al[4];
      #pragma unroll
      for (int rt = 0; rt < 4; ++rt) {
        uint32_t byte = axor((uint32_t)((rt*16 + kt)*1024 + lane*16));
        ah[rt] = *(const short8*)(ldsHi + byte);
        al[rt] = *(const short8*)(ldsLo + byte);
      }
      #pragma unroll
      for (int c2 = 0; c2 < 2; ++c2) {
        short8 b = *(const short8*)(pHd + c2*1024);
        #pragma unroll
        for (int rt = 0; rt < 4; ++rt) {
          o[rt][c2] = MFMA16(ah[rt], b, o[rt][c2]);
          o[rt][c2] = MFMA16(al[rt], b, o[rt][c2]);
        }
      }
      pHd += 16384;
    }
  }
  const size_t rowg = (size_t)rb*BROWS;
  #pragma unroll
  for (int rt = 0; rt < 4; ++rt)
    #pragma unroll
    for (int c2 = 0; c2 < 2; ++c2)
      #pragma unroll
      for (int r = 0; r < 4; ++r) {
        size_t row = rowg + rt*16 + ql*4 + r;
        out[row*OUTD + oc[c2]] = o[rt][c2][r];
      }
}

extern "C" void kernel_launch(void* const* d_in, const int* in_sizes, int n_in,
                              void* d_out, int out_size, void* d_ws, size_t ws_size,
                              hipStream_t stream)
{
  const float* x    = (const float*)d_in[0];
  const float* winw = (const float*)d_in[1];
  const float* winb = (const float*)d_in[2];
  const float* lw   = (const float*)d_in[3];
  const float* lb   = (const float*)d_in[4];
  const float* lu   = (const float*)d_in[5];
  const float* ow   = (const float*)d_in[6];
  const float* ou   = (const float*)d_in[7];
  const float* hw   = (const float*)d_in[8];
  const float* hb   = (const float*)d_in[9];
  const int*   st   = (const int*)d_in[10];
  float* out = (float*)d_out;
  char*  ws  = (char*)d_ws;

  float* invs   = (float*)(ws);
  float* bsum   = (float*)(ws + 1024);
  float* cs     = (float*)(ws + 4096);
  float* cn     = (float*)(ws + 8192);
  short* packWh = (short*)(ws + 16384);                 // 512 KiB
  short* packWl = (short*)(ws + 16384 + 524288);        // 512 KiB
  short* packIh = (short*)(ws + 1064960);               // 256 KiB
  short* packIl = (short*)(ws + 1327104);               // 256 KiB
  short* packHd = (short*)(ws + 1589248);               // 256 KiB

  sigma_kernel<<<4, 512, 0, stream>>>(lw, lu, ow, ou, invs);
  pack_wsum<<<1024, 256, 0, stream>>>(lw, invs, packWh, packWl);
  pack_b<256, 512, true><<<512, 256, 0, stream>>>(winw, packIh, packIl);
  pack_b<512, 256, false><<<512, 256, 0, stream>>>(hw, packHd, nullptr);
  pack_small<<<2, 256, 0, stream>>>(lb, ow, invs, bsum, cs, cn);

  hipFuncSetAttribute((const void*)fused_main,
                      hipFuncAttributeMaxDynamicSharedMemorySize, 131072);
  fused_main<<<65536/BROWS, 512, 131072, stream>>>(x, winb, hb, st,
                                                   packWh, packWl, packIh, packIl, packHd,
                                                   bsum, cs, cn, out);
}

// Round 6
// 4139.412 us; speedup vs baseline: 1.1044x; 1.1044x over previous
//
#include <hip/hip_runtime.h>
#include <stdint.h>

#define HID 512
#define IND 256
#define OUTD 256
#define BROWS 64

typedef __attribute__((ext_vector_type(8))) short short8;   // 8 bf16
typedef __attribute__((ext_vector_type(4))) short short4v;  // 4 bf16
typedef __attribute__((ext_vector_type(4))) float f32x4;
typedef __attribute__((ext_vector_type(4))) int   i32x4;

#define MFMA16(a,b,c) __builtin_amdgcn_mfma_f32_16x16x32_bf16(a,b,c,0,0,0)

__device__ __forceinline__ short f2bf(float f){
  uint32_t u = __builtin_bit_cast(uint32_t, f);
  u += 0x7FFFu + ((u>>16)&1u);
  return (short)(u>>16);
}
__device__ __forceinline__ float bf2f(short s){
  uint32_t u = ((uint32_t)(uint16_t)s) << 16;
  return __builtin_bit_cast(float, u);
}
// pack one f32 as (hi bf16 | lo bf16) in one u32; unpack = hi + lo
__device__ __forceinline__ int pack_hl(float v){
  short hi = f2bf(v);
  short lo = f2bf(v - bf2f(hi));
  return (((int)(uint16_t)hi) << 16) | (int)(uint16_t)lo;
}
__device__ __forceinline__ float unpk(int p){
  float vh = __builtin_bit_cast(float, (uint32_t)p & 0xFFFF0000u);
  float vl = __builtin_bit_cast(float, (uint32_t)p << 16);
  return vh + vl;
}
__device__ __forceinline__ float tanh_fast(float x){
  float e = __builtin_amdgcn_exp2f(x * 2.88539008177792681472f);
  return __builtin_fmaf(-2.0f, __builtin_amdgcn_rcpf(e + 1.0f), 1.0f);
}
__device__ __forceinline__ float neigh(float v){
  // lane^1 exchange via DPP quad_perm [1,0,3,2]
  return __builtin_bit_cast(float,
      __builtin_amdgcn_mov_dpp(__builtin_bit_cast(int, v), 0xB1, 0xF, 0xF, true));
}
__device__ __forceinline__ uint32_t axor(uint32_t b){ return b ^ (((b>>7)&7u)<<4); }

// ---------------- sigma: one power-iteration step, one block per matrix ----------------
__global__ void sigma_kernel(const float* __restrict__ lw, const float* __restrict__ lu,
                             const float* __restrict__ ow, const float* __restrict__ ou,
                             float* __restrict__ invs)
{
  __shared__ float sv[HID];
  __shared__ float red[8];
  const int g = threadIdx.x;  // 512 threads
  const int m = blockIdx.x;   // 0..3
  const float* W = (m < 3) ? (lw + (size_t)m*HID*HID) : ow;
  const float* u = (m < 3) ? (lu + m*HID) : ou;
  float t1 = 0.f;
  for (int k = 0; k < HID; ++k) t1 += W[(size_t)k*HID + g] * u[k];
  float ss = t1*t1;
  #pragma unroll
  for (int d = 32; d; d >>= 1) ss += __shfl_xor(ss, d);
  if ((g & 63) == 0) red[g >> 6] = ss;
  __syncthreads();
  float tot = 0.f;
  #pragma unroll
  for (int i = 0; i < 8; ++i) tot += red[i];
  float nrm = sqrtf(tot);
  sv[g] = t1 / (nrm + 1e-12f);
  __syncthreads();
  float n = 0.f;
  const float* Wr = W + (size_t)g*HID;
  for (int k = 0; k < HID; ++k) n += Wr[k] * sv[k];
  float ss2 = n*n;
  #pragma unroll
  for (int d = 32; d; d >>= 1) ss2 += __shfl_xor(ss2, d);
  if ((g & 63) == 0) red[g >> 6] = ss2;
  __syncthreads();
  float tot2 = 0.f;
  #pragma unroll
  for (int i = 0; i < 8; ++i) tot2 += red[i];
  float nn = sqrtf(tot2);
  float sigma = tot2 / (nn + 1e-12f);   // dot(u2, Wv)
  if (g == 0) invs[m] = 1.0f / sigma;
}

// ---------------- weight packing (hi + lo bf16), MFMA-frag-sequential ----------------
// B-frag (16x16x32): lane l holds B[k = kt*32 + (l>>4)*8 + j][col = ctg*16 + (l&15)],
// element index ((kt*NCT+ctg)*64 + l)*8 + j.
__global__ void pack_wsum(const float* __restrict__ lw, const float* __restrict__ invs,
                          short* __restrict__ pwh, short* __restrict__ pwl)
{
  int i = blockIdx.x*blockDim.x + threadIdx.x;   // < 512*512
  int j = i & 7, lane = (i >> 3) & 63, f = i >> 9;
  int kt = f >> 5, ctg = f & 31;                 // NCT = 32
  int k = kt*32 + (lane >> 4)*8 + j;
  int g = ctg*16 + (lane & 15);
  size_t idx = (size_t)g*HID + k;
  float v = lw[idx]*invs[0] + lw[262144 + idx]*invs[1] + lw[524288 + idx]*invs[2];
  short hi = f2bf(v);
  pwh[i] = hi;
  pwl[i] = f2bf(v - bf2f(hi));
}

template<int K, int N, bool WLO>
__global__ void pack_b(const float* __restrict__ W, short* __restrict__ pbh,
                       short* __restrict__ pbl)
{
  int i = blockIdx.x*blockDim.x + threadIdx.x;   // < K*N
  int j = i & 7, lane = (i >> 3) & 63, f = i >> 9;
  constexpr int NCT = N/16;
  int kt = f / NCT, ctg = f % NCT;
  int k = kt*32 + (lane >> 4)*8 + j;
  int c = ctg*16 + (lane & 15);
  float v = W[(size_t)c*K + k];
  short hi = f2bf(v);
  pbh[i] = hi;
  if (WLO) pbl[i] = f2bf(v - bf2f(hi));
}

__global__ void pack_small(const float* __restrict__ lb, const float* __restrict__ ow,
                           const float* __restrict__ invs,
                           float* __restrict__ bsum, float* __restrict__ cs, float* __restrict__ cn)
{
  int g = blockIdx.x*blockDim.x + threadIdx.x;
  if (g >= HID) return;
  bsum[g] = lb[g] + lb[HID + g] + lb[2*HID + g];
  float is = invs[3];
  cs[g] = ow[(size_t)g*HID + g] * is;        // osc_sn[g][g]
  cn[g] = ow[(size_t)g*HID + (g^1)] * is;    // osc_sn[g][g^1]
}

// ---------------- fused main: 64-row block, 1024 threads (16 waves), designed for the
// 128-VGPR cap: wave tile 32x64 (wr 2 x wc 8), 32 outputs/thread.
// Per-thread state: h[2][4] f32 (32) + xe packed hi/lo bf16 (32 u32) + 2 osc scalars
// + ct-half transients (acc 16 + frags 24) ~= 125 regs -> zero spills at 128.
// LDS 128 KiB (A hi/lo) -> 1 block/CU, 16 waves = 4 waves/SIMD occupancy.
__global__ void __launch_bounds__(1024) fused_main(
    const float* __restrict__ x,
    const float* __restrict__ winb,
    const float* __restrict__ headb,
    const int*  __restrict__ stepsp,
    const short* __restrict__ packWh,
    const short* __restrict__ packWl,
    const short* __restrict__ packIh,
    const short* __restrict__ packIl,
    const short* __restrict__ packHd,
    const float* __restrict__ bsumA,
    const float* __restrict__ csA,
    const float* __restrict__ cnA,
    float* __restrict__ out)
{
  extern __shared__ char lds[];     // 128 KiB: [A_hi 64K][A_lo 64K], frag-major
  char* ldsHi = lds;
  char* ldsLo = lds + 65536;
  const int tid  = threadIdx.x;
  const int lane = tid & 63;
  const int l15  = lane & 15;
  const int ql   = lane >> 4;       // 0..3
  const int wid  = tid >> 6;        // 0..15
  const int wr   = wid >> 3;        // 0..1  (row half: 32 rows)
  const int wc   = wid & 7;         // 0..7  (col group: 64 cols)
  const int rb   = blockIdx.x;

  // ---- stage x tile -> LDS bf16 hi/lo, frag-major [rtg 0..3][kt 0..7] ----
  {
    const float* xb = x + (size_t)rb*BROWS*IND;
    #pragma unroll
    for (int i = 0; i < 4; ++i) {
      int fi  = i*1024 + tid;       // 4096 float4s
      int row = fi >> 6;            // 0..63
      int c   = (fi & 63)*4;        // 0..252
      f32x4 v = *(const f32x4*)(xb + (size_t)row*IND + c);
      short4v hi4, lo4;
      #pragma unroll
      for (int j = 0; j < 4; ++j) {
        short h16 = f2bf(v[j]);
        hi4[j] = h16;
        lo4[j] = f2bf(v[j] - bf2f(h16));
      }
      int rtg = row >> 4, kt = c >> 5, qd = (c >> 3) & 3;
      uint32_t byte = (uint32_t)(((rtg*8 + kt)*1024) + (qd*16 + (row & 15))*16 + (c & 7)*2);
      *(short4v*)(ldsHi + axor(byte)) = hi4;
      *(short4v*)(ldsLo + axor(byte)) = lo4;
    }
  }
  __syncthreads();

  const int nsteps = stepsp[0];

  // Oscillator coefficients: uniform 2x2 rotation blocks => cs is per-column-parity
  // invariant and cn flips sign with parity; all 4 ct share this thread's values.
  const float cs_s = csA[wc*64 + l15];
  const float cn_s = cnA[wc*64 + l15];

  // byte-base pointers for frag-sequential weight streams (per-lane)
  const char* baseWh = (const char*)packWh + (size_t)wc*4096 + (size_t)lane*16;
  const char* baseWl = (const char*)packWl + (size_t)wc*4096 + (size_t)lane*16;

  // ---- x_emb = x @ W_in^T + W_in_b + b_sum  (3-pass split precision) ----
  f32x4 xe[2][4];
  #pragma unroll
  for (int ct = 0; ct < 4; ++ct) {
    int c = wc*64 + ct*16 + l15;
    float s = winb[c] + bsumA[c];
    #pragma unroll
    for (int rt = 0; rt < 2; ++rt) {
      f32x4 z; z[0]=s; z[1]=s; z[2]=s; z[3]=s;
      xe[rt][ct] = z;
    }
  }
  {
    const char* pIh = (const char*)packIh + (size_t)wc*4096 + (size_t)lane*16;
    const char* pIl = (const char*)packIl + (size_t)wc*4096 + (size_t)lane*16;
    #pragma unroll 2
    for (int kt = 0; kt < 8; ++kt) {
      short8 ah[2], al[2];
      #pragma unroll
      for (int rt = 0; rt < 2; ++rt) {
        uint32_t byte = axor((uint32_t)(((wr*2 + rt)*8 + kt)*1024 + lane*16));
        ah[rt] = *(const short8*)(ldsHi + byte);
        al[rt] = *(const short8*)(ldsLo + byte);
      }
      #pragma unroll
      for (int ct = 0; ct < 4; ++ct) {
        short8 bh = *(const short8*)(pIh + ct*1024);
        short8 bl = *(const short8*)(pIl + ct*1024);
        #pragma unroll
        for (int rt = 0; rt < 2; ++rt) {
          xe[rt][ct] = MFMA16(ah[rt], bh, xe[rt][ct]);
          xe[rt][ct] = MFMA16(al[rt], bh, xe[rt][ct]);
          xe[rt][ct] = MFMA16(ah[rt], bl, xe[rt][ct]);
        }
      }
      pIh += 32768; pIl += 32768;
    }
  }
  __syncthreads();

  // ---- h init: h1 = 0.5*tanh(xe); then pack xe to hi/lo bf16 (1 u32 per elem) ----
  f32x4 h[2][4];
  i32x4 xp[2][4];
  #pragma unroll
  for (int rt = 0; rt < 2; ++rt)
    #pragma unroll
    for (int ct = 0; ct < 4; ++ct)
      #pragma unroll
      for (int r = 0; r < 4; ++r) {
        float v = xe[rt][ct][r];
        h[rt][ct][r] = (nsteps >= 1) ? 0.5f * tanh_fast(v) : 0.f;
        xp[rt][ct][r] = pack_hl(v);
      }

  // ---- recurrence steps 2..nsteps ----
  for (int s = 1; s < nsteps; ++s) {
    // t = tanh(h) -> LDS hi/lo A-tiles (this wave's 32 rows, its 64 cols as K-slices)
    #pragma unroll
    for (int rt = 0; rt < 2; ++rt) {
      uint32_t rcomp = (uint32_t)((wr*2 + rt)*16384);
      #pragma unroll
      for (int ct = 0; ct < 4; ++ct) {
        int c = wc*64 + ct*16 + l15;
        uint32_t wcomp = (uint32_t)(((c >> 5)*1024) + (((c >> 3) & 3)*256) + ((c & 7)*2) + ql*64);
        #pragma unroll
        for (int r = 0; r < 4; ++r) {
          float t = tanh_fast(h[rt][ct][r]);
          short hi16 = f2bf(t);
          uint32_t byte = axor(rcomp + wcomp + (uint32_t)(r*16));
          *(short*)(ldsHi + byte) = hi16;
          *(short*)(ldsLo + byte) = f2bf(t - bf2f(hi16));
        }
      }
    }
    __syncthreads();

    #pragma unroll
    for (int ch = 0; ch < 2; ++ch) {      // ct-halves: acc only 16 regs live
      f32x4 acc[2][2];
      #pragma unroll
      for (int rt = 0; rt < 2; ++rt)
        #pragma unroll
        for (int c2 = 0; c2 < 2; ++c2) {
          int ct = ch*2 + c2;
          #pragma unroll
          for (int r = 0; r < 4; ++r) {
            float hv = h[rt][ct][r];
            acc[rt][c2][r] = __builtin_fmaf(cs_s, hv,
                               __builtin_fmaf(cn_s, neigh(hv), unpk(xp[rt][ct][r])));
          }
        }
      const char* pWh_ = baseWh + ch*2048;
      const char* pWl_ = baseWl + ch*2048;
      #pragma unroll 1
      for (int kt = 0; kt < 16; ++kt) {
        short8 ah[2], al[2];
        #pragma unroll
        for (int rt = 0; rt < 2; ++rt) {
          uint32_t byte = axor((uint32_t)(((wr*2 + rt)*16 + kt)*1024 + lane*16));
          ah[rt] = *(const short8*)(ldsHi + byte);
          al[rt] = *(const short8*)(ldsLo + byte);
        }
        #pragma unroll
        for (int c2 = 0; c2 < 2; ++c2) {
          short8 bh = *(const short8*)(pWh_ + c2*1024);
          short8 bl = *(const short8*)(pWl_ + c2*1024);
          #pragma unroll
          for (int rt = 0; rt < 2; ++rt) {
            acc[rt][c2] = MFMA16(ah[rt], bh, acc[rt][c2]);
            acc[rt][c2] = MFMA16(al[rt], bh, acc[rt][c2]);
            acc[rt][c2] = MFMA16(ah[rt], bl, acc[rt][c2]);
          }
        }
        pWh_ += 32768; pWl_ += 32768;
      }
      #pragma unroll
      for (int rt = 0; rt < 2; ++rt)
        #pragma unroll
        for (int c2 = 0; c2 < 2; ++c2) {
          int ct = ch*2 + c2;
          #pragma unroll
          for (int r = 0; r < 4; ++r)
            h[rt][ct][r] = __builtin_fmaf(0.5f, tanh_fast(acc[rt][c2][r]), 0.5f*h[rt][ct][r]);
        }
    }
    __syncthreads();
  }

  // ---- head: out = h @ head_w^T + head_b  (A split hi/lo, W single bf16) ----
  #pragma unroll
  for (int rt = 0; rt < 2; ++rt) {
    uint32_t rcomp = (uint32_t)((wr*2 + rt)*16384);
    #pragma unroll
    for (int ct = 0; ct < 4; ++ct) {
      int c = wc*64 + ct*16 + l15;
      uint32_t wcomp = (uint32_t)(((c >> 5)*1024) + (((c >> 3) & 3)*256) + ((c & 7)*2) + ql*64);
      #pragma unroll
      for (int r = 0; r < 4; ++r) {
        float hv = h[rt][ct][r];
        short hi16 = f2bf(hv);
        uint32_t byte = axor(rcomp + wcomp + (uint32_t)(r*16));
        *(short*)(ldsHi + byte) = hi16;
        *(short*)(ldsLo + byte) = f2bf(hv - bf2f(hi16));
      }
    }
  }
  __syncthreads();

  int oc[2]; float hbv[2];
  #pragma unroll
  for (int c2 = 0; c2 < 2; ++c2) { oc[c2] = wc*32 + c2*16 + l15; hbv[c2] = headb[oc[c2]]; }
  f32x4 o[2][2];
  #pragma unroll
  for (int rt = 0; rt < 2; ++rt)
    #pragma unroll
    for (int c2 = 0; c2 < 2; ++c2) {
      f32x4 z; z[0]=hbv[c2]; z[1]=hbv[c2]; z[2]=hbv[c2]; z[3]=hbv[c2];
      o[rt][c2] = z;
    }
  {
    const char* pHd = (const char*)packHd + (size_t)wc*2048 + (size_t)lane*16;
    #pragma unroll 2
    for (int kt = 0; kt < 16; ++kt) {
      short8 ah[2], al[2];
      #pragma unroll
      for (int rt = 0; rt < 2; ++rt) {
        uint32_t byte = axor((uint32_t)(((wr*2 + rt)*16 + kt)*1024 + lane*16));
        ah[rt] = *(const short8*)(ldsHi + byte);
        al[rt] = *(const short8*)(ldsLo + byte);
      }
      #pragma unroll
      for (int c2 = 0; c2 < 2; ++c2) {
        short8 b = *(const short8*)(pHd + c2*1024);
        #pragma unroll
        for (int rt = 0; rt < 2; ++rt) {
          o[rt][c2] = MFMA16(ah[rt], b, o[rt][c2]);
          o[rt][c2] = MFMA16(al[rt], b, o[rt][c2]);
        }
      }
      pHd += 16384;
    }
  }
  const size_t rowg = (size_t)rb*BROWS + wr*32;
  #pragma unroll
  for (int rt = 0; rt < 2; ++rt)
    #pragma unroll
    for (int c2 = 0; c2 < 2; ++c2)
      #pragma unroll
      for (int r = 0; r < 4; ++r) {
        size_t row = rowg + rt*16 + ql*4 + r;
        out[row*OUTD + oc[c2]] = o[rt][c2][r];
      }
}

extern "C" void kernel_launch(void* const* d_in, const int* in_sizes, int n_in,
                              void* d_out, int out_size, void* d_ws, size_t ws_size,
                              hipStream_t stream)
{
  const float* x    = (const float*)d_in[0];
  const float* winw = (const float*)d_in[1];
  const float* winb = (const float*)d_in[2];
  const float* lw   = (const float*)d_in[3];
  const float* lb   = (const float*)d_in[4];
  const float* lu   = (const float*)d_in[5];
  const float* ow   = (const float*)d_in[6];
  const float* ou   = (const float*)d_in[7];
  const float* hw   = (const float*)d_in[8];
  const float* hb   = (const float*)d_in[9];
  const int*   st   = (const int*)d_in[10];
  float* out = (float*)d_out;
  char*  ws  = (char*)d_ws;

  float* invs   = (float*)(ws);
  float* bsum   = (float*)(ws + 1024);
  float* cs     = (float*)(ws + 4096);
  float* cn     = (float*)(ws + 8192);
  short* packWh = (short*)(ws + 16384);                 // 512 KiB
  short* packWl = (short*)(ws + 16384 + 524288);        // 512 KiB
  short* packIh = (short*)(ws + 1064960);               // 256 KiB
  short* packIl = (short*)(ws + 1327104);               // 256 KiB
  short* packHd = (short*)(ws + 1589248);               // 256 KiB

  sigma_kernel<<<4, 512, 0, stream>>>(lw, lu, ow, ou, invs);
  pack_wsum<<<1024, 256, 0, stream>>>(lw, invs, packWh, packWl);
  pack_b<256, 512, true><<<512, 256, 0, stream>>>(winw, packIh, packIl);
  pack_b<512, 256, false><<<512, 256, 0, stream>>>(hw, packHd, nullptr);
  pack_small<<<2, 256, 0, stream>>>(lb, ow, invs, bsum, cs, cn);

  hipFuncSetAttribute((const void*)fused_main,
                      hipFuncAttributeMaxDynamicSharedMemorySize, 131072);
  fused_main<<<65536/BROWS, 1024, 131072, stream>>>(x, winb, hb, st,
                                                    packWh, packWl, packIh, packIl, packHd,
                                                    bsum, cs, cn, out);
}